// Round 2
// baseline (2349.852 us; speedup 1.0000x reference)
//
#include <hip/hip_runtime.h>
#include <hip/hip_fp16.h>
#include <math.h>

// Problem constants
#define N_ROWS 32768
#define K_CODES 8192
#define DIM 512

// Output layout (floats): quantized_st[N,D], probs[N,K], loss, perplexity
#define OUT_Q 0
#define OUT_P ((size_t)N_ROWS * DIM)                       // 16777216
#define OUT_LOSS (OUT_P + (size_t)N_ROWS * K_CODES)        // 285212672
#define OUT_PERP (OUT_LOSS + 1)

// Workspace layout (float offsets). NO contended accumulators: per-row error
// array reduced by finalize; histogram uses spread atomics only.
#define WS_WSQ 0                        // 8192 floats
#define WS_CNT (K_CODES)                // 8192 floats (histogram)
#define WS_ERR (2 * K_CODES)            // 32768 floats (per-row sq-err)
#define WS_F16 (2 * K_CODES + N_ROWS)   // 49152: f16 base (byte 196608, 16-aligned)

// f16 region layout (in _Float16 elements, relative to f16 base)
#define XH_OFF ((size_t)0)
#define XL_OFF ((size_t)N_ROWS * DIM)
#define WH_OFF ((size_t)2 * N_ROWS * DIM)
#define WL_OFF ((size_t)2 * N_ROWS * DIM + (size_t)K_CODES * DIM)
#define F16_COUNT ((size_t)2 * (N_ROWS + K_CODES) * DIM)   // 41943040 halves
#define WS_NEEDED ((size_t)WS_F16 * 4 + F16_COUNT * 2)     // ~84.1 MB

typedef _Float16 f16x8 __attribute__((ext_vector_type(8)));
typedef float f32x4 __attribute__((ext_vector_type(4)));

__device__ inline void load_lds16(const void* g, void* l) {
    __builtin_amdgcn_global_load_lds((const __attribute__((address_space(1))) void*)g,
                                     (__attribute__((address_space(3))) void*)l,
                                     16, 0, 0);
}

// Monotone float->uint key: uint order == float order (handles negatives).
__device__ inline unsigned int fkey(float f) {
    unsigned int b = __float_as_uint(f);
    return b ^ ((unsigned int)((int)b >> 31) | 0x80000000u);
}
__device__ inline float fkey_inv(unsigned int k) {
    unsigned int b = (k & 0x80000000u) ? (k ^ 0x80000000u) : ~k;
    return __uint_as_float(b);
}

// ---------------------------------------------------------------------------
// Kernel 0 (fallback path only): row squared norms for W.
// ---------------------------------------------------------------------------
__global__ void wsq_kernel(const float* __restrict__ W, float* __restrict__ ws) {
    int row = blockIdx.x;
    int lane = threadIdx.x;  // 0..63
    const float* src = W + (size_t)row * DIM;
    float4 v0 = *(const float4*)(src + lane * 8);
    float4 v1 = *(const float4*)(src + lane * 8 + 4);
    float s = v0.x * v0.x + v0.y * v0.y + v0.z * v0.z + v0.w * v0.w
            + v1.x * v1.x + v1.y * v1.y + v1.z * v1.z + v1.w * v1.w;
#pragma unroll
    for (int off = 32; off > 0; off >>= 1) s += __shfl_down(s, off, 64);
    if (lane == 0) ws[WS_WSQ + row] = s;
}

// ---------------------------------------------------------------------------
// Kernel 0b: split X and W into fp16 hi/lo pairs + fused W row norms.
// ---------------------------------------------------------------------------
__global__ void __launch_bounds__(256) convert_split_kernel(
    const float* __restrict__ X, const float* __restrict__ W,
    _Float16* __restrict__ f16base, float* __restrict__ ws) {
    const size_t NX8 = (size_t)N_ROWS * DIM / 8;  // 2097152
    size_t t = (size_t)blockIdx.x * 256 + threadIdx.x;
    const float* src;
    _Float16 *hd, *ld;
    bool isW = (t >= NX8);
    if (!isW) {
        src = X + t * 8;
        hd = f16base + XH_OFF + t * 8;
        ld = f16base + XL_OFF + t * 8;
    } else {
        size_t u = t - NX8;
        src = W + u * 8;
        hd = f16base + WH_OFF + u * 8;
        ld = f16base + WL_OFF + u * 8;
    }
    float4 v0 = *(const float4*)src;
    float4 v1 = *(const float4*)(src + 4);
    float v[8] = {v0.x, v0.y, v0.z, v0.w, v1.x, v1.y, v1.z, v1.w};
    f16x8 h, l;
    float s = 0.f;
#pragma unroll
    for (int i = 0; i < 8; ++i) {
        _Float16 hv = (_Float16)v[i];
        h[i] = hv;
        l[i] = (_Float16)(v[i] - (float)hv);
        s += v[i] * v[i];
    }
    *(f16x8*)hd = h;
    *(f16x8*)ld = l;
    if (isW) {  // wave-uniform branch (W region is wave-aligned)
#pragma unroll
        for (int off = 32; off > 0; off >>= 1) s += __shfl_down(s, off, 64);
        if ((threadIdx.x & 63) == 0) ws[WS_WSQ + ((t - NX8) >> 6)] = s;
    }
}

// ---------------------------------------------------------------------------
// Kernel 1 (MFMA): S[m,n] = wsq[n] - 2 * (x_m . w_n) via fp16 3-term split.
// BM=256 x BN=128, BK=32, 512 threads (8 waves 4x2), triple-buffered LDS,
// 2-deep prefetch, counted vmcnt(6). NEW this round: 4 phases per K-step,
// each phase = {2-10 ds_read (+stage)} -> barrier -> lgkmcnt(0) ->
// sched_barrier -> setprio(1) -> 12-MFMA cluster -> setprio(0) -> barrier.
// (m201 template discipline: one clean lgkm drain per cluster, trailing
// barrier creates the wave role-split that makes setprio pay.)
// XCD swizzle: each XCD owns an 8-tile bn stripe -> its W slice (2.1 MB)
// stays L2-resident; A-tiles reused by 8 consecutive same-XCD blocks.
// ---------------------------------------------------------------------------
#define LDSB 24576   // halves per buffer (Ah 8192 | Al 8192 | Bh 4096 | Bl 4096)
#define AH_O 0
#define AL_O 8192
#define BH_O 16384
#define BL_O 20480

__global__ void __launch_bounds__(512, 2) gemm_dist_mfma_kernel(
    const _Float16* __restrict__ f16base, const float* __restrict__ ws,
    float* __restrict__ out) {
    __shared__ _Float16 lds[3 * LDSB];  // 144 KiB

    const int tid = threadIdx.x;
    const int w = tid >> 6;     // wave 0..7
    const int lane = tid & 63;

    // XCD-aware 2D swizzle (bijective, 8192 blocks, round-robin dispatch):
    // xcd = lin&7; per-XCD: bn stripe of 8 tiles (W slice L2-resident),
    // bm advances every 8 blocks (A-tile reused 8x while L2-hot).
    int lin = blockIdx.y * 64 + blockIdx.x;
    int xcd = lin & 7;
    int idx = lin >> 3;
    const int bn = (xcd * 8 + (idx & 7)) * 128;   // 64 bn tiles
    const int bm = (idx >> 3) * 256;              // 128 bm tiles

    const int wr = w >> 1;      // m-quadrant 0..3 (64 rows each)
    const int wc = w & 1;       // n-half     0..1 (64 cols each)
    const int q = lane >> 4;    // frag k-chunk 0..3
    const int fm = lane & 15;   // frag row/col within 16
    const int l4 = lane >> 2;   // stage: row within 16-row group
    const int p = lane & 3;     // stage: chunk position

    f32x4 acc[4][4];
#pragma unroll
    for (int i = 0; i < 4; ++i)
#pragma unroll
        for (int j = 0; j < 4; ++j) acc[i][j] = (f32x4){0.f, 0.f, 0.f, 0.f};

    // Stage one K-step part into buf. part 0: A group w*2 (h+l) + Bh group w.
    // part 1: A group w*2+1 (h+l) + Bl group w.  3 loads/thread per part.
    auto stage = [&](int ks, _Float16* buf, int part) {
        const int kk = ks * 32;
        int g = w * 2 + part;
        int arow = g * 16 + l4;
        int ca = p ^ ((arow >> 1) & 3);
        size_t aoff = (size_t)(bm + arow) * DIM + kk + ca * 8;
        load_lds16(f16base + XH_OFF + aoff, buf + AH_O + g * 512);
        load_lds16(f16base + XL_OFF + aoff, buf + AL_O + g * 512);
        int brow = w * 16 + l4;
        int cb = p ^ ((brow >> 1) & 3);
        size_t boff = (size_t)(bn + brow) * DIM + kk + cb * 8;
        if (part == 0)
            load_lds16(f16base + WH_OFF + boff, buf + BH_O + w * 512);
        else
            load_lds16(f16base + WL_OFF + boff, buf + BL_O + w * 512);
    };

    _Float16* c0 = lds;
    _Float16* c1 = lds + LDSB;
    _Float16* c2 = lds + 2 * LDSB;

    // Prologue: stage ks0 -> c0 (6 loads), ks1 -> c1 (6 loads); wait for c0.
    stage(0, c0, 0); stage(0, c0, 1);
    stage(1, c1, 0); stage(1, c1, 1);
    asm volatile("s_waitcnt vmcnt(6)" ::: "memory");
    __builtin_amdgcn_s_barrier();
    __builtin_amdgcn_sched_barrier(0);

#pragma unroll 1
    for (int ks = 0; ks < 16; ++ks) {
        f16x8 bhv[4], blv[4];

        // readA: fragment (h,l) for m-subtile i from current buffer
        auto readA = [&](int i, f16x8& h, f16x8& l) {
            int am = wr * 64 + i * 16 + fm;
            int off = am * 32 + ((q ^ ((am >> 1) & 3)) * 8);
            h = *(const f16x8*)&c0[AH_O + off];
            l = *(const f16x8*)&c0[AL_O + off];
        };
        // 12-MFMA cluster for m-subtile i (3-term f16 split x 4 j)
        auto cluster = [&](int i, f16x8 h, f16x8 l) {
#pragma unroll
            for (int j = 0; j < 4; ++j) {
                acc[i][j] = __builtin_amdgcn_mfma_f32_16x16x32_f16(
                    h, bhv[j], acc[i][j], 0, 0, 0);
                acc[i][j] = __builtin_amdgcn_mfma_f32_16x16x32_f16(
                    h, blv[j], acc[i][j], 0, 0, 0);
                acc[i][j] = __builtin_amdgcn_mfma_f32_16x16x32_f16(
                    l, bhv[j], acc[i][j], 0, 0, 0);
            }
        };

        // ---- phase 0: B frags (8) + A0 (2); stage part 0 of ks+2 ----
#pragma unroll
        for (int j = 0; j < 4; ++j) {
            int bb = wc * 64 + j * 16 + fm;
            int off = bb * 32 + ((q ^ ((bb >> 1) & 3)) * 8);
            bhv[j] = *(const f16x8*)&c0[BH_O + off];
            blv[j] = *(const f16x8*)&c0[BL_O + off];
        }
        f16x8 a0h, a0l;
        readA(0, a0h, a0l);
        if (ks < 14) stage(ks + 2, c2, 0);
        __builtin_amdgcn_s_barrier();
        asm volatile("s_waitcnt lgkmcnt(0)" ::: "memory");
        __builtin_amdgcn_sched_barrier(0);
        __builtin_amdgcn_s_setprio(1);
        cluster(0, a0h, a0l);
        __builtin_amdgcn_s_setprio(0);
        __builtin_amdgcn_s_barrier();

        // ---- phase 1: A1 (2) ----
        f16x8 a1h, a1l;
        readA(1, a1h, a1l);
        __builtin_amdgcn_s_barrier();
        asm volatile("s_waitcnt lgkmcnt(0)" ::: "memory");
        __builtin_amdgcn_sched_barrier(0);
        __builtin_amdgcn_s_setprio(1);
        cluster(1, a1h, a1l);
        __builtin_amdgcn_s_setprio(0);
        __builtin_amdgcn_s_barrier();

        // ---- phase 2: A2 (2); stage part 1 of ks+2 ----
        f16x8 a2h, a2l;
        readA(2, a2h, a2l);
        if (ks < 14) stage(ks + 2, c2, 1);
        __builtin_amdgcn_s_barrier();
        asm volatile("s_waitcnt lgkmcnt(0)" ::: "memory");
        __builtin_amdgcn_sched_barrier(0);
        __builtin_amdgcn_s_setprio(1);
        cluster(2, a2h, a2l);
        __builtin_amdgcn_s_setprio(0);
        __builtin_amdgcn_s_barrier();

        // ---- phase 3: A3 (2); counted vmcnt at K-step end ----
        f16x8 a3h, a3l;
        readA(3, a3h, a3l);
        __builtin_amdgcn_s_barrier();
        asm volatile("s_waitcnt lgkmcnt(0)" ::: "memory");
        __builtin_amdgcn_sched_barrier(0);
        __builtin_amdgcn_s_setprio(1);
        cluster(3, a3h, a3l);
        __builtin_amdgcn_s_setprio(0);
        // Retire buffer (ks+1)'s 6 loads; keep (ks+2)'s 6 in flight.
        if (ks < 14) {
            asm volatile("s_waitcnt vmcnt(6)" ::: "memory");
        } else if (ks == 14) {
            asm volatile("s_waitcnt vmcnt(0)" ::: "memory");
        }
        __builtin_amdgcn_s_barrier();
        __builtin_amdgcn_sched_barrier(0);

        _Float16* t0 = c0; c0 = c1; c1 = c2; c2 = t0;
    }

    // Epilogue: S = wsq[n] - 2*dot (pure store).
    // C/D layout: col = lane&15, row = (lane>>4)*4 + r (m89-verified)
    const float* wsq = ws + WS_WSQ;
    float* Dout = out + OUT_P;
    const int q4 = q * 4;
#pragma unroll
    for (int i = 0; i < 4; ++i) {
#pragma unroll
        for (int j = 0; j < 4; ++j) {
            int n = bn + wc * 64 + j * 16 + fm;
            float wn = wsq[n];
#pragma unroll
            for (int r = 0; r < 4; ++r) {
                int m = bm + wr * 64 + i * 16 + q4 + r;
                Dout[(size_t)m * K_CODES + n] = wn - 2.f * acc[i][j][r];
            }
        }
    }
}

// ---------------------------------------------------------------------------
// Fallback fp32 GEMM (only if ws can't hold f16 buffers): writes S.
// ---------------------------------------------------------------------------
#define BM 128
#define BN 128
#define BK 16

__global__ void __launch_bounds__(256) gemm_dist_fp32_kernel(
    const float* __restrict__ X, const float* __restrict__ W,
    const float* __restrict__ ws, float* __restrict__ out) {
    __shared__ float As[BK][BM];
    __shared__ float Bs[BK][BN];

    const int bn = blockIdx.x * BN;
    const int bm = blockIdx.y * BM;
    const int tid = threadIdx.x;
    const int tx = tid & 15;
    const int ty = tid >> 4;
    const int lr = tid >> 1;
    const int lc = (tid & 1) * 8;

    float acc[8][8];
#pragma unroll
    for (int i = 0; i < 8; ++i)
#pragma unroll
        for (int j = 0; j < 8; ++j) acc[i][j] = 0.f;

    const float* aptr = X + (size_t)(bm + lr) * DIM + lc;
    const float* bptr = W + (size_t)(bn + lr) * DIM + lc;

    for (int k0 = 0; k0 < DIM; k0 += BK) {
        float4 a0 = *(const float4*)(aptr + k0);
        float4 a1 = *(const float4*)(aptr + k0 + 4);
        float4 b0 = *(const float4*)(bptr + k0);
        float4 b1 = *(const float4*)(bptr + k0 + 4);
        __syncthreads();
        As[lc + 0][lr] = a0.x; As[lc + 1][lr] = a0.y;
        As[lc + 2][lr] = a0.z; As[lc + 3][lr] = a0.w;
        As[lc + 4][lr] = a1.x; As[lc + 5][lr] = a1.y;
        As[lc + 6][lr] = a1.z; As[lc + 7][lr] = a1.w;
        Bs[lc + 0][lr] = b0.x; Bs[lc + 1][lr] = b0.y;
        Bs[lc + 2][lr] = b0.z; Bs[lc + 3][lr] = b0.w;
        Bs[lc + 4][lr] = b1.x; Bs[lc + 5][lr] = b1.y;
        Bs[lc + 6][lr] = b1.z; Bs[lc + 7][lr] = b1.w;
        __syncthreads();
#pragma unroll
        for (int kk = 0; kk < BK; ++kk) {
            float a[8], b[8];
            *(float4*)&a[0] = *(const float4*)&As[kk][ty * 8];
            *(float4*)&a[4] = *(const float4*)&As[kk][ty * 8 + 4];
            *(float4*)&b[0] = *(const float4*)&Bs[kk][tx * 8];
            *(float4*)&b[4] = *(const float4*)&Bs[kk][tx * 8 + 4];
#pragma unroll
            for (int i = 0; i < 8; ++i)
#pragma unroll
                for (int j = 0; j < 8; ++j)
                    acc[i][j] = fmaf(a[i], b[j], acc[i][j]);
        }
    }

    const float* wsq = ws + WS_WSQ;
    const int m0 = bm + ty * 8;
    const int n0 = bn + tx * 8;
    float wn[8];
    *(float4*)&wn[0] = *(const float4*)(wsq + n0);
    *(float4*)&wn[4] = *(const float4*)(wsq + n0 + 4);
    float* Dout = out + OUT_P;
#pragma unroll
    for (int i = 0; i < 8; ++i) {
        float4 o0, o1;
        o0.x = wn[0] - 2.f * acc[i][0];
        o0.y = wn[1] - 2.f * acc[i][1];
        o0.z = wn[2] - 2.f * acc[i][2];
        o0.w = wn[3] - 2.f * acc[i][3];
        o1.x = wn[4] - 2.f * acc[i][4];
        o1.y = wn[5] - 2.f * acc[i][5];
        o1.z = wn[6] - 2.f * acc[i][6];
        o1.w = wn[7] - 2.f * acc[i][7];
        float* drow = Dout + (size_t)(m0 + i) * K_CODES + n0;
        *(float4*)(drow) = o0;
        *(float4*)(drow + 4) = o1;
    }
}

// ---------------------------------------------------------------------------
// Kernel 2 (fused): one block per row. Register-stage the S row; packed
// (min,argmin) from registers; softmax in place; gather W[amin]; write
// quantized_st; per-row sq-err to ws (NON-atomic); spread histogram atomic.
// ---------------------------------------------------------------------------
__global__ void __launch_bounds__(256) probs_quant_kernel(
    const float* __restrict__ X, const float* __restrict__ W,
    float* __restrict__ out, float* __restrict__ ws) {
    const int n = blockIdx.x;
    const int tid = threadIdx.x;
    __shared__ unsigned long long mred[4];
    __shared__ float fred[4];

    float4* Drow4 = (float4*)(out + OUT_P + (size_t)n * K_CODES);

    // Independent X load issued up front (hides under row processing).
    const float2* xr = (const float2*)(X + (size_t)n * DIM);
    float2 x = xr[tid];

    // Load row into registers; packed min (key<<32 | col) on the fly.
    float4 e[8];
    unsigned long long best = ~0ull;
#pragma unroll
    for (int t = 0; t < 8; ++t) {
        float4 v = Drow4[tid + t * 256];
        e[t] = v;
        unsigned int c0 = (unsigned int)((tid + t * 256) * 4);
        unsigned long long k;
        k = ((unsigned long long)fkey(v.x) << 32) | (c0 + 0u);
        best = k < best ? k : best;
        k = ((unsigned long long)fkey(v.y) << 32) | (c0 + 1u);
        best = k < best ? k : best;
        k = ((unsigned long long)fkey(v.z) << 32) | (c0 + 2u);
        best = k < best ? k : best;
        k = ((unsigned long long)fkey(v.w) << 32) | (c0 + 3u);
        best = k < best ? k : best;
    }
#pragma unroll
    for (int d = 1; d < 64; d <<= 1) {
        unsigned long long o = __shfl_xor(best, d, 64);
        best = o < best ? o : best;
    }
    if ((tid & 63) == 0) mred[tid >> 6] = best;
    __syncthreads();
    unsigned long long bm = mred[0];
    bm = mred[1] < bm ? mred[1] : bm;
    bm = mred[2] < bm ? mred[2] : bm;
    bm = mred[3] < bm ? mred[3] : bm;
    const float smin = fkey_inv((unsigned int)(bm >> 32));
    const int amin = (int)(bm & 0xFFFFFFFFu);

    // exp(smin - s) in registers; block sum.
    float sum = 0.f;
#pragma unroll
    for (int t = 0; t < 8; ++t) {
        float4 v = e[t];
        float4 ev;
        ev.x = __expf(smin - v.x);
        ev.y = __expf(smin - v.y);
        ev.z = __expf(smin - v.z);
        ev.w = __expf(smin - v.w);
        e[t] = ev;
        sum += ev.x + ev.y + ev.z + ev.w;
    }
#pragma unroll
    for (int off = 32; off > 0; off >>= 1) sum += __shfl_down(sum, off, 64);
    if ((tid & 63) == 0) fred[tid >> 6] = sum;
    __syncthreads();
    const float inv = 1.0f / (fred[0] + fred[1] + fred[2] + fred[3]);

    // normalized store (in place)
#pragma unroll
    for (int t = 0; t < 8; ++t) {
        float4 ev = e[t];
        ev.x *= inv; ev.y *= inv; ev.z *= inv; ev.w *= inv;
        Drow4[tid + t * 256] = ev;
    }

    // quantize + straight-through + per-row error (2 floats per thread)
    const float2* wr = (const float2*)(W + (size_t)amin * DIM);
    float2* qr = (float2*)(out + OUT_Q + (size_t)n * DIM);
    float2 qv = wr[tid];
    float2 d2, o;
    d2.x = qv.x - x.x; d2.y = qv.y - x.y;
    o.x = x.x + d2.x;  o.y = x.y + d2.y;
    qr[tid] = o;
    float err = d2.x * d2.x + d2.y * d2.y;
#pragma unroll
    for (int off = 32; off > 0; off >>= 1) err += __shfl_down(err, off, 64);
    __syncthreads();  // WAR: everyone done reading fred before overwrite
    if ((tid & 63) == 0) fred[tid >> 6] = err;
    __syncthreads();
    if (tid == 0) {
        ws[WS_ERR + n] = fred[0] + fred[1] + fred[2] + fred[3];
        atomicAdd(ws + WS_CNT + amin, 1.0f);  // spread over 8192 addrs
    }
}

// ---------------------------------------------------------------------------
// Kernel 3: finalize loss (reduce per-row errors) + perplexity (counts).
// ---------------------------------------------------------------------------
__global__ void __launch_bounds__(1024) finalize_kernel(
    float* __restrict__ out, const float* __restrict__ ws) {
    __shared__ float red[1024];
    const int tid = threadIdx.x;

    float errsum = 0.f;
    for (int j = tid; j < N_ROWS; j += 1024) errsum += ws[WS_ERR + j];
    red[tid] = errsum;
    __syncthreads();
    for (int st = 512; st > 0; st >>= 1) {
        if (tid < st) red[tid] += red[tid + st];
        __syncthreads();
    }
    const float total_err = red[0];
    __syncthreads();

    float ent = 0.f;
    for (int j = tid; j < K_CODES; j += 1024) {
        float p = ws[WS_CNT + j] * (1.0f / (float)N_ROWS);
        ent -= p * logf(p + 1e-10f);
    }
    red[tid] = ent;
    __syncthreads();
    for (int st = 512; st > 0; st >>= 1) {
        if (tid < st) red[tid] += red[tid + st];
        __syncthreads();
    }
    if (tid == 0) {
        float mse = total_err * (1.0f / ((float)N_ROWS * (float)DIM));
        out[OUT_LOSS] = mse + 0.25f * mse;
        out[OUT_PERP] = expf(red[0]);
    }
}

// ---------------------------------------------------------------------------
extern "C" void kernel_launch(void* const* d_in, const int* in_sizes, int n_in,
                              void* d_out, int out_size, void* d_ws, size_t ws_size,
                              hipStream_t stream) {
    const float* X = (const float*)d_in[0];  // [32768, 512]
    const float* W = (const float*)d_in[1];  // [8192, 512]
    float* out = (float*)d_out;
    float* ws = (float*)d_ws;

    // zero the histogram (ws is poisoned 0xAA); WS_ERR is fully overwritten
    hipMemsetAsync(ws + WS_CNT, 0, K_CODES * sizeof(float), stream);

    if (ws_size >= WS_NEEDED) {
        _Float16* f16base = (_Float16*)(ws + WS_F16);
        const int conv_blocks =
            (int)(((size_t)(N_ROWS + K_CODES) * DIM / 8 + 255) / 256);
        // convert also computes wsq (fused W row-norms)
        convert_split_kernel<<<conv_blocks, 256, 0, stream>>>(X, W, f16base, ws);

        dim3 ggrid(64, 128);  // bn-tiles x bm-tiles
        gemm_dist_mfma_kernel<<<ggrid, 512, 0, stream>>>(f16base, ws, out);
    } else {
        wsq_kernel<<<K_CODES, 64, 0, stream>>>(W, ws);
        dim3 ggrid(K_CODES / BN, N_ROWS / BM);
        gemm_dist_fp32_kernel<<<ggrid, 256, 0, stream>>>(X, W, ws, out);
    }

    probs_quant_kernel<<<N_ROWS, 256, 0, stream>>>(X, W, out, ws);
    finalize_kernel<<<1, 1024, 0, stream>>>(out, ws);
}

// Round 3
// 2348.527 us; speedup vs baseline: 1.0006x; 1.0006x over previous
//
#include <hip/hip_runtime.h>
#include <hip/hip_fp16.h>
#include <math.h>

// Problem constants
#define N_ROWS 32768
#define K_CODES 8192
#define DIM 512

// Output layout (floats): quantized_st[N,D], probs[N,K], loss, perplexity
#define OUT_Q 0
#define OUT_P ((size_t)N_ROWS * DIM)                       // 16777216
#define OUT_LOSS (OUT_P + (size_t)N_ROWS * K_CODES)        // 285212672
#define OUT_PERP (OUT_LOSS + 1)

// Workspace layout (float offsets). NO contended accumulators: per-row error
// array reduced by finalize; histogram uses spread atomics only.
#define WS_WSQ 0                        // 8192 floats
#define WS_CNT (K_CODES)                // 8192 floats (histogram)
#define WS_ERR (2 * K_CODES)            // 32768 floats (per-row sq-err)
#define WS_RED (2 * K_CODES + N_ROWS)   // 64 floats (finalize partials, fully overwritten)
#define WS_F16 (2 * K_CODES + N_ROWS + 64)  // f16 base (byte 196864, 16-aligned)

// f16 region layout (in _Float16 elements, relative to f16 base)
#define XH_OFF ((size_t)0)
#define XL_OFF ((size_t)N_ROWS * DIM)
#define WH_OFF ((size_t)2 * N_ROWS * DIM)
#define WL_OFF ((size_t)2 * N_ROWS * DIM + (size_t)K_CODES * DIM)
#define F16_COUNT ((size_t)2 * (N_ROWS + K_CODES) * DIM)   // 41943040 halves
#define WS_NEEDED ((size_t)WS_F16 * 4 + F16_COUNT * 2)     // ~84.1 MB

typedef _Float16 f16x8 __attribute__((ext_vector_type(8)));
typedef float f32x4 __attribute__((ext_vector_type(4)));

__device__ inline void load_lds16(const void* g, void* l) {
    __builtin_amdgcn_global_load_lds((const __attribute__((address_space(1))) void*)g,
                                     (__attribute__((address_space(3))) void*)l,
                                     16, 0, 0);
}

// Monotone float->uint key: uint order == float order (handles negatives).
__device__ inline unsigned int fkey(float f) {
    unsigned int b = __float_as_uint(f);
    return b ^ ((unsigned int)((int)b >> 31) | 0x80000000u);
}
__device__ inline float fkey_inv(unsigned int k) {
    unsigned int b = (k & 0x80000000u) ? (k ^ 0x80000000u) : ~k;
    return __uint_as_float(b);
}

// ---------------------------------------------------------------------------
// Kernel 0 (fallback path only): row squared norms for W.
// ---------------------------------------------------------------------------
__global__ void wsq_kernel(const float* __restrict__ W, float* __restrict__ ws) {
    int row = blockIdx.x;
    int lane = threadIdx.x;  // 0..63
    const float* src = W + (size_t)row * DIM;
    float4 v0 = *(const float4*)(src + lane * 8);
    float4 v1 = *(const float4*)(src + lane * 8 + 4);
    float s = v0.x * v0.x + v0.y * v0.y + v0.z * v0.z + v0.w * v0.w
            + v1.x * v1.x + v1.y * v1.y + v1.z * v1.z + v1.w * v1.w;
#pragma unroll
    for (int off = 32; off > 0; off >>= 1) s += __shfl_down(s, off, 64);
    if (lane == 0) ws[WS_WSQ + row] = s;
}

// ---------------------------------------------------------------------------
// Kernel 0b: split X and W into fp16 hi/lo pairs + fused W row norms.
// ---------------------------------------------------------------------------
__global__ void __launch_bounds__(256) convert_split_kernel(
    const float* __restrict__ X, const float* __restrict__ W,
    _Float16* __restrict__ f16base, float* __restrict__ ws) {
    const size_t NX8 = (size_t)N_ROWS * DIM / 8;  // 2097152
    size_t t = (size_t)blockIdx.x * 256 + threadIdx.x;
    const float* src;
    _Float16 *hd, *ld;
    bool isW = (t >= NX8);
    if (!isW) {
        src = X + t * 8;
        hd = f16base + XH_OFF + t * 8;
        ld = f16base + XL_OFF + t * 8;
    } else {
        size_t u = t - NX8;
        src = W + u * 8;
        hd = f16base + WH_OFF + u * 8;
        ld = f16base + WL_OFF + u * 8;
    }
    float4 v0 = *(const float4*)src;
    float4 v1 = *(const float4*)(src + 4);
    float v[8] = {v0.x, v0.y, v0.z, v0.w, v1.x, v1.y, v1.z, v1.w};
    f16x8 h, l;
    float s = 0.f;
#pragma unroll
    for (int i = 0; i < 8; ++i) {
        _Float16 hv = (_Float16)v[i];
        h[i] = hv;
        l[i] = (_Float16)(v[i] - (float)hv);
        s += v[i] * v[i];
    }
    *(f16x8*)hd = h;
    *(f16x8*)ld = l;
    if (isW) {  // wave-uniform branch (W region is wave-aligned)
#pragma unroll
        for (int off = 32; off > 0; off >>= 1) s += __shfl_down(s, off, 64);
        if ((threadIdx.x & 63) == 0) ws[WS_WSQ + ((t - NX8) >> 6)] = s;
    }
}

// ---------------------------------------------------------------------------
// Kernel 1 (MFMA): S[m,n] = wsq[n] - 2 * (x_m . w_n) via fp16 3-term split.
// BM=256 x BN=128, BK=32, 512 threads (8 waves 4x2), triple-buffered LDS,
// 2-deep prefetch, counted vmcnt(6).
// Round-3 schedule: ONE barrier per K-step. Issue the 6 global_load_lds
// first (issue-early), then all 16 ds_read_b128, then the 48-MFMA region
// (16 independent 3-chains). Compiler staggers lgkmcnt inside the MFMA
// region (verified behavior); single sync point lets the 2 waves/SIMD
// drift and cover each other's waits. (Round-2's 4-phase split exposed
// the LDS latency 4x/K-step with all waves stalling together - reverted.)
// XCD swizzle (kept from round 2, FETCH halved): each XCD owns an 8-tile
// bn stripe -> its W slice (2.1 MB) stays L2-resident; A-tile reused by 8
// consecutive same-XCD blocks.
// ---------------------------------------------------------------------------
#define LDSB 24576   // halves per buffer (Ah 8192 | Al 8192 | Bh 4096 | Bl 4096)
#define AH_O 0
#define AL_O 8192
#define BH_O 16384
#define BL_O 20480

__global__ void __launch_bounds__(512, 2) gemm_dist_mfma_kernel(
    const _Float16* __restrict__ f16base, const float* __restrict__ ws,
    float* __restrict__ out) {
    __shared__ _Float16 lds[3 * LDSB];  // 144 KiB

    const int tid = threadIdx.x;
    const int w = tid >> 6;     // wave 0..7
    const int lane = tid & 63;

    // XCD-aware 2D swizzle (bijective, 8192 blocks, round-robin dispatch):
    // xcd = lin&7; per-XCD: bn stripe of 8 tiles (W slice L2-resident),
    // bm advances every 8 blocks (A-tile reused 8x while L2-hot).
    int lin = blockIdx.y * 64 + blockIdx.x;
    int xcd = lin & 7;
    int idx = lin >> 3;
    const int bn = (xcd * 8 + (idx & 7)) * 128;   // 64 bn tiles
    const int bm = (idx >> 3) * 256;              // 128 bm tiles

    const int wr = w >> 1;      // m-quadrant 0..3 (64 rows each)
    const int wc = w & 1;       // n-half     0..1 (64 cols each)
    const int q = lane >> 4;    // frag k-chunk 0..3
    const int fm = lane & 15;   // frag row/col within 16
    const int l4 = lane >> 2;   // stage: row within 16-row group
    const int p = lane & 3;     // stage: chunk position

    f32x4 acc[4][4];
#pragma unroll
    for (int i = 0; i < 4; ++i)
#pragma unroll
        for (int j = 0; j < 4; ++j) acc[i][j] = (f32x4){0.f, 0.f, 0.f, 0.f};

    // Stage one K-step part into buf. part 0: A group w*2 (h+l) + Bh group w.
    // part 1: A group w*2+1 (h+l) + Bl group w.  3 loads/thread per part.
    auto stage = [&](int ks, _Float16* buf, int part) {
        const int kk = ks * 32;
        int g = w * 2 + part;
        int arow = g * 16 + l4;
        int ca = p ^ ((arow >> 1) & 3);
        size_t aoff = (size_t)(bm + arow) * DIM + kk + ca * 8;
        load_lds16(f16base + XH_OFF + aoff, buf + AH_O + g * 512);
        load_lds16(f16base + XL_OFF + aoff, buf + AL_O + g * 512);
        int brow = w * 16 + l4;
        int cb = p ^ ((brow >> 1) & 3);
        size_t boff = (size_t)(bn + brow) * DIM + kk + cb * 8;
        if (part == 0)
            load_lds16(f16base + WH_OFF + boff, buf + BH_O + w * 512);
        else
            load_lds16(f16base + WL_OFF + boff, buf + BL_O + w * 512);
    };

    _Float16* c0 = lds;
    _Float16* c1 = lds + LDSB;
    _Float16* c2 = lds + 2 * LDSB;

    // Prologue: stage ks0 -> c0 (6 loads), ks1 -> c1 (6 loads); wait for c0.
    stage(0, c0, 0); stage(0, c0, 1);
    stage(1, c1, 0); stage(1, c1, 1);
    asm volatile("s_waitcnt vmcnt(6)" ::: "memory");
    __builtin_amdgcn_s_barrier();
    __builtin_amdgcn_sched_barrier(0);

#pragma unroll 1
    for (int ks = 0; ks < 16; ++ks) {
        // Issue next-next K-step staging first (HBM latency hides under
        // this K-step's ds_reads + MFMAs). Target c2 = buffer all waves
        // finished reading last iteration (end-of-iter barrier protects).
        if (ks < 14) { stage(ks + 2, c2, 0); stage(ks + 2, c2, 1); }

        // All 16 fragment reads for this K-step from current buffer c0.
        f16x8 bhv[4], blv[4], ahv[4], alv[4];
#pragma unroll
        for (int j = 0; j < 4; ++j) {
            int bb = wc * 64 + j * 16 + fm;
            int off = bb * 32 + ((q ^ ((bb >> 1) & 3)) * 8);
            bhv[j] = *(const f16x8*)&c0[BH_O + off];
            blv[j] = *(const f16x8*)&c0[BL_O + off];
        }
#pragma unroll
        for (int i = 0; i < 4; ++i) {
            int am = wr * 64 + i * 16 + fm;
            int off = am * 32 + ((q ^ ((am >> 1) & 3)) * 8);
            ahv[i] = *(const f16x8*)&c0[AH_O + off];
            alv[i] = *(const f16x8*)&c0[AL_O + off];
        }

        // 48 MFMA: 16 independent (i,j) chains of 3 (hh, hl, lh terms).
        __builtin_amdgcn_s_setprio(1);
#pragma unroll
        for (int i = 0; i < 4; ++i)
#pragma unroll
            for (int j = 0; j < 4; ++j) {
                acc[i][j] = __builtin_amdgcn_mfma_f32_16x16x32_f16(
                    ahv[i], bhv[j], acc[i][j], 0, 0, 0);
                acc[i][j] = __builtin_amdgcn_mfma_f32_16x16x32_f16(
                    ahv[i], blv[j], acc[i][j], 0, 0, 0);
                acc[i][j] = __builtin_amdgcn_mfma_f32_16x16x32_f16(
                    alv[i], bhv[j], acc[i][j], 0, 0, 0);
            }
        __builtin_amdgcn_s_setprio(0);

        // Counted wait: retire buffer (ks+1)'s 6 loads; keep (ks+2)'s 6
        // in flight across the barrier (never drain to 0 in steady state).
        if (ks < 14) {
            asm volatile("s_waitcnt vmcnt(6)" ::: "memory");
        } else if (ks == 14) {
            asm volatile("s_waitcnt vmcnt(0)" ::: "memory");
        }
        __builtin_amdgcn_s_barrier();
        __builtin_amdgcn_sched_barrier(0);

        _Float16* t0 = c0; c0 = c1; c1 = c2; c2 = t0;
    }

    // Epilogue: S = wsq[n] - 2*dot (pure store).
    // C/D layout: col = lane&15, row = (lane>>4)*4 + r (m89-verified)
    const float* wsq = ws + WS_WSQ;
    float* Dout = out + OUT_P;
    const int q4 = q * 4;
#pragma unroll
    for (int i = 0; i < 4; ++i) {
#pragma unroll
        for (int j = 0; j < 4; ++j) {
            int n = bn + wc * 64 + j * 16 + fm;
            float wn = wsq[n];
#pragma unroll
            for (int r = 0; r < 4; ++r) {
                int m = bm + wr * 64 + i * 16 + q4 + r;
                Dout[(size_t)m * K_CODES + n] = wn - 2.f * acc[i][j][r];
            }
        }
    }
}

// ---------------------------------------------------------------------------
// Fallback fp32 GEMM (only if ws can't hold f16 buffers): writes S.
// ---------------------------------------------------------------------------
#define BM 128
#define BN 128
#define BK 16

__global__ void __launch_bounds__(256) gemm_dist_fp32_kernel(
    const float* __restrict__ X, const float* __restrict__ W,
    const float* __restrict__ ws, float* __restrict__ out) {
    __shared__ float As[BK][BM];
    __shared__ float Bs[BK][BN];

    const int bn = blockIdx.x * BN;
    const int bm = blockIdx.y * BM;
    const int tid = threadIdx.x;
    const int tx = tid & 15;
    const int ty = tid >> 4;
    const int lr = tid >> 1;
    const int lc = (tid & 1) * 8;

    float acc[8][8];
#pragma unroll
    for (int i = 0; i < 8; ++i)
#pragma unroll
        for (int j = 0; j < 8; ++j) acc[i][j] = 0.f;

    const float* aptr = X + (size_t)(bm + lr) * DIM + lc;
    const float* bptr = W + (size_t)(bn + lr) * DIM + lc;

    for (int k0 = 0; k0 < DIM; k0 += BK) {
        float4 a0 = *(const float4*)(aptr + k0);
        float4 a1 = *(const float4*)(aptr + k0 + 4);
        float4 b0 = *(const float4*)(bptr + k0);
        float4 b1 = *(const float4*)(bptr + k0 + 4);
        __syncthreads();
        As[lc + 0][lr] = a0.x; As[lc + 1][lr] = a0.y;
        As[lc + 2][lr] = a0.z; As[lc + 3][lr] = a0.w;
        As[lc + 4][lr] = a1.x; As[lc + 5][lr] = a1.y;
        As[lc + 6][lr] = a1.z; As[lc + 7][lr] = a1.w;
        Bs[lc + 0][lr] = b0.x; Bs[lc + 1][lr] = b0.y;
        Bs[lc + 2][lr] = b0.z; Bs[lc + 3][lr] = b0.w;
        Bs[lc + 4][lr] = b1.x; Bs[lc + 5][lr] = b1.y;
        Bs[lc + 6][lr] = b1.z; Bs[lc + 7][lr] = b1.w;
        __syncthreads();
#pragma unroll
        for (int kk = 0; kk < BK; ++kk) {
            float a[8], b[8];
            *(float4*)&a[0] = *(const float4*)&As[kk][ty * 8];
            *(float4*)&a[4] = *(const float4*)&As[kk][ty * 8 + 4];
            *(float4*)&b[0] = *(const float4*)&Bs[kk][tx * 8];
            *(float4*)&b[4] = *(const float4*)&Bs[kk][tx * 8 + 4];
#pragma unroll
            for (int i = 0; i < 8; ++i)
#pragma unroll
                for (int j = 0; j < 8; ++j)
                    acc[i][j] = fmaf(a[i], b[j], acc[i][j]);
        }
    }

    const float* wsq = ws + WS_WSQ;
    const int m0 = bm + ty * 8;
    const int n0 = bn + tx * 8;
    float wn[8];
    *(float4*)&wn[0] = *(const float4*)(wsq + n0);
    *(float4*)&wn[4] = *(const float4*)(wsq + n0 + 4);
    float* Dout = out + OUT_P;
#pragma unroll
    for (int i = 0; i < 8; ++i) {
        float4 o0, o1;
        o0.x = wn[0] - 2.f * acc[i][0];
        o0.y = wn[1] - 2.f * acc[i][1];
        o0.z = wn[2] - 2.f * acc[i][2];
        o0.w = wn[3] - 2.f * acc[i][3];
        o1.x = wn[4] - 2.f * acc[i][4];
        o1.y = wn[5] - 2.f * acc[i][5];
        o1.z = wn[6] - 2.f * acc[i][6];
        o1.w = wn[7] - 2.f * acc[i][7];
        float* drow = Dout + (size_t)(m0 + i) * K_CODES + n0;
        *(float4*)(drow) = o0;
        *(float4*)(drow + 4) = o1;
    }
}

// ---------------------------------------------------------------------------
// Kernel 2 (fused): one block (512 thr) per row. Register-stage the S row;
// packed (min,argmin) from registers; softmax in place; gather W[amin];
// write quantized_st; per-row sq-err to ws (NON-atomic); spread histogram.
// 512 threads (was 256): 2x load-issue parallelism per block.
// ---------------------------------------------------------------------------
__global__ void __launch_bounds__(512) probs_quant_kernel(
    const float* __restrict__ X, const float* __restrict__ W,
    float* __restrict__ out, float* __restrict__ ws) {
    const int n = blockIdx.x;
    const int tid = threadIdx.x;
    __shared__ unsigned long long mred[8];
    __shared__ float fred[8];

    float4* Drow4 = (float4*)(out + OUT_P + (size_t)n * K_CODES);

    // Independent X load issued up front (hides under row processing).
    const float x = X[(size_t)n * DIM + tid];

    // Load row into registers; packed min (key<<32 | col) on the fly.
    float4 e[4];
    unsigned long long best = ~0ull;
#pragma unroll
    for (int t = 0; t < 4; ++t) {
        float4 v = Drow4[tid + t * 512];
        e[t] = v;
        unsigned int c0 = (unsigned int)((tid + t * 512) * 4);
        unsigned long long k;
        k = ((unsigned long long)fkey(v.x) << 32) | (c0 + 0u);
        best = k < best ? k : best;
        k = ((unsigned long long)fkey(v.y) << 32) | (c0 + 1u);
        best = k < best ? k : best;
        k = ((unsigned long long)fkey(v.z) << 32) | (c0 + 2u);
        best = k < best ? k : best;
        k = ((unsigned long long)fkey(v.w) << 32) | (c0 + 3u);
        best = k < best ? k : best;
    }
#pragma unroll
    for (int d = 1; d < 64; d <<= 1) {
        unsigned long long o = __shfl_xor(best, d, 64);
        best = o < best ? o : best;
    }
    if ((tid & 63) == 0) mred[tid >> 6] = best;
    __syncthreads();
    unsigned long long bm = mred[0];
#pragma unroll
    for (int i = 1; i < 8; ++i) bm = mred[i] < bm ? mred[i] : bm;
    const float smin = fkey_inv((unsigned int)(bm >> 32));
    const int amin = (int)(bm & 0xFFFFFFFFu);

    // exp(smin - s) in registers; block sum.
    float sum = 0.f;
#pragma unroll
    for (int t = 0; t < 4; ++t) {
        float4 v = e[t];
        float4 ev;
        ev.x = __expf(smin - v.x);
        ev.y = __expf(smin - v.y);
        ev.z = __expf(smin - v.z);
        ev.w = __expf(smin - v.w);
        e[t] = ev;
        sum += ev.x + ev.y + ev.z + ev.w;
    }
#pragma unroll
    for (int off = 32; off > 0; off >>= 1) sum += __shfl_down(sum, off, 64);
    if ((tid & 63) == 0) fred[tid >> 6] = sum;
    __syncthreads();
    float tot = fred[0];
#pragma unroll
    for (int i = 1; i < 8; ++i) tot += fred[i];
    const float inv = 1.0f / tot;

    // normalized store (in place)
#pragma unroll
    for (int t = 0; t < 4; ++t) {
        float4 ev = e[t];
        ev.x *= inv; ev.y *= inv; ev.z *= inv; ev.w *= inv;
        Drow4[tid + t * 512] = ev;
    }

    // quantize + straight-through + per-row error (1 float per thread)
    const float qv = W[(size_t)amin * DIM + tid];
    out[OUT_Q + (size_t)n * DIM + tid] = qv;  // x + (q - x) == q exactly
    float d2 = qv - x;
    float err = d2 * d2;
#pragma unroll
    for (int off = 32; off > 0; off >>= 1) err += __shfl_down(err, off, 64);
    __syncthreads();  // WAR: everyone done reading fred before overwrite
    if ((tid & 63) == 0) fred[tid >> 6] = err;
    __syncthreads();
    if (tid == 0) {
        float e8 = fred[0];
#pragma unroll
        for (int i = 1; i < 8; ++i) e8 += fred[i];
        ws[WS_ERR + n] = e8;
        atomicAdd(ws + WS_CNT + amin, 1.0f);  // spread over 8192 addrs
    }
}

// ---------------------------------------------------------------------------
// Kernel 3a: 32-block partial reduce of per-row errors + entropy terms.
// Partials fully overwritten -> no memset needed for WS_RED.
// ---------------------------------------------------------------------------
__global__ void __launch_bounds__(256) finalize_part_kernel(
    float* __restrict__ ws) {
    __shared__ float red[256];
    const int b = blockIdx.x;   // 0..31
    const int tid = threadIdx.x;

    float errsum = 0.f;
    const int ebase = b * 1024;  // 32768/32
#pragma unroll
    for (int j = tid; j < 1024; j += 256) errsum += ws[WS_ERR + ebase + j];

    float p = ws[WS_CNT + b * 256 + tid] * (1.0f / (float)N_ROWS);  // 8192/32
    float ent = -p * logf(p + 1e-10f);

    red[tid] = errsum;
    __syncthreads();
    for (int st = 128; st > 0; st >>= 1) {
        if (tid < st) red[tid] += red[tid + st];
        __syncthreads();
    }
    if (tid == 0) ws[WS_RED + b] = red[0];
    __syncthreads();
    red[tid] = ent;
    __syncthreads();
    for (int st = 128; st > 0; st >>= 1) {
        if (tid < st) red[tid] += red[tid + st];
        __syncthreads();
    }
    if (tid == 0) ws[WS_RED + 32 + b] = red[0];
}

// ---------------------------------------------------------------------------
// Kernel 3b: final combine (one wave).
// ---------------------------------------------------------------------------
__global__ void __launch_bounds__(64) finalize_fin_kernel(
    float* __restrict__ out, const float* __restrict__ ws) {
    const int tid = threadIdx.x;
    float ev = tid < 32 ? ws[WS_RED + tid] : 0.f;
    float nv = tid < 32 ? ws[WS_RED + 32 + tid] : 0.f;
#pragma unroll
    for (int off = 32; off > 0; off >>= 1) {
        ev += __shfl_down(ev, off, 64);
        nv += __shfl_down(nv, off, 64);
    }
    if (tid == 0) {
        float mse = ev * (1.0f / ((float)N_ROWS * (float)DIM));
        out[OUT_LOSS] = mse + 0.25f * mse;
        out[OUT_PERP] = expf(nv);
    }
}

// ---------------------------------------------------------------------------
extern "C" void kernel_launch(void* const* d_in, const int* in_sizes, int n_in,
                              void* d_out, int out_size, void* d_ws, size_t ws_size,
                              hipStream_t stream) {
    const float* X = (const float*)d_in[0];  // [32768, 512]
    const float* W = (const float*)d_in[1];  // [8192, 512]
    float* out = (float*)d_out;
    float* ws = (float*)d_ws;

    // zero the histogram (ws is poisoned 0xAA); WS_ERR/WS_RED fully overwritten
    hipMemsetAsync(ws + WS_CNT, 0, K_CODES * sizeof(float), stream);

    if (ws_size >= WS_NEEDED) {
        _Float16* f16base = (_Float16*)(ws + WS_F16);
        const int conv_blocks =
            (int)(((size_t)(N_ROWS + K_CODES) * DIM / 8 + 255) / 256);
        // convert also computes wsq (fused W row-norms)
        convert_split_kernel<<<conv_blocks, 256, 0, stream>>>(X, W, f16base, ws);

        dim3 ggrid(64, 128);  // bn-tiles x bm-tiles
        gemm_dist_mfma_kernel<<<ggrid, 512, 0, stream>>>(f16base, ws, out);
    } else {
        wsq_kernel<<<K_CODES, 64, 0, stream>>>(W, ws);
        dim3 ggrid(K_CODES / BN, N_ROWS / BM);
        gemm_dist_fp32_kernel<<<ggrid, 256, 0, stream>>>(X, W, ws, out);
    }

    probs_quant_kernel<<<N_ROWS, 512, 0, stream>>>(X, W, out, ws);
    finalize_part_kernel<<<32, 256, 0, stream>>>(ws);
    finalize_fin_kernel<<<1, 64, 0, stream>>>(out, ws);
}